// Round 10
// baseline (5373.265 us; speedup 1.0000x reference)
//
#include <hip/hip_runtime.h>
#include <stdint.h>

// NpiLstm: T=512, B=128, H=1024, IN=64 (63 x-features + 1 feedback)
// Feedback folded into recurrent weights: W_hh' = W_hh + w_fb (x) W_lin.
// R10: INT8 weights (per-gate-column scale) + two-channel int8 h (hi + lo
// residual) -> per-wave weight fragments = 80 VGPRs, genuinely register-
// resident (bf16's 294KB/block could never be; streaming it from L2 was
// ~2.1us/step — R5-R8 evidence). i8 MFMA 16x16x64 (2x bf16 rate).
// Geometry: 512 blocks (2/CU, co-resident blocks hide IC latency);
// 8 groups x 64 blocks; group g = batch rows [16g,16g+16); block mb owns
// h-cols [16mb,16mb+16). Waves K-split (x + 4 h-tiles each), i32 partials
// scaled to f32 in-wave, one barrier/step. sc0 sc1 exchange (proven R2/R5).

typedef int int4v __attribute__((ext_vector_type(4)));
typedef float float4v __attribute__((ext_vector_type(4)));

#define C_HI  (1.0f/127.0f)
#define C_HLO (1.0f/32258.0f)   // h lo-channel: h ~ qhi/127 + qlo/32258
#define C_XLO (1.0f/16129.0f)   // x lo-channel: x ~ sx*(qhi/127 + qlo/16129)

__device__ __forceinline__ float sigm(float x) { return 1.0f / (1.0f + __expf(-x)); }
__device__ __forceinline__ float tanh_f(float x) {
  float ax = fabsf(x);
  float e = __expf(-2.0f * ax);
  float r = (1.0f - e) / (1.0f + e);
  return x < 0.0f ? -r : r;
}
#define MFMA_I8(A, B, C) __builtin_amdgcn_mfma_i32_16x16x64_i8((A), (B), (C), 0, 0, 0)

// ---- zero h planes + flags + sx bits (must run FIRST) ----
__global__ void initz(unsigned int* __restrict__ Hhi, unsigned int* __restrict__ Hlo,
                      int* __restrict__ flags, unsigned int* __restrict__ sxu) {
  int idx = blockIdx.x * 256 + threadIdx.x;   // 0..65535
  Hhi[idx] = 0u;                               // 2 parities x 128 x 1024 bytes
  Hlo[idx] = 0u;
  if (idx < 2048) flags[idx] = 0;
  if (idx == 0) *sxu = 0u;
}

// ---- global amax of x -> sx ----
__global__ void prep_ax(const float* __restrict__ x, unsigned int* __restrict__ sxu) {
  int tid = blockIdx.x * 256 + threadIdx.x;   // 1024 blocks
  float am = 0.f;
  for (int i = tid; i < 4128768; i += 262144) am = fmaxf(am, fabsf(x[i]));
  for (int d = 1; d < 64; d <<= 1) am = fmaxf(am, __shfl_xor(am, d));
  __shared__ float sam[4];
  if ((threadIdx.x & 63) == 0) sam[threadIdx.x >> 6] = am;
  __syncthreads();
  if (threadIdx.x == 0) {
    float m = fmaxf(fmaxf(sam[0], sam[1]), fmaxf(sam[2], sam[3]));
    atomicMax(sxu, __float_as_uint(m));   // floats >= 0: bit order = value order
  }
}

// ---- fold weights, per-column amax, quantize to int8; biases ----
// Wq row j (gate-col), k-layout: [0,64) = x-block (63 feats + 1 zero),
// [64,1088) = h-block (folded W_hh). 1088 = 17 tiles of K=64.
__global__ void prep_wq(const float* __restrict__ W_ih, const float* __restrict__ W_hh,
                        const float* __restrict__ W_lin, const float* __restrict__ b_ih,
                        const float* __restrict__ b_hh, const float* __restrict__ b_lin,
                        signed char* __restrict__ Wq, float* __restrict__ scol,
                        float* __restrict__ b1, float* __restrict__ b2) {
  int j = blockIdx.x;          // 0..4095
  int tid = threadIdx.x;
  float wfb = W_ih[j * 64 + 63];
  float wv[5];
  float am = 0.f;
#pragma unroll
  for (int it = 0; it < 5; ++it) {
    int k = tid + 256 * it;
    float w = 0.f;
    if (k < 63) w = W_ih[j * 64 + k];
    else if (k >= 64 && k < 1088) {
      int kk = k - 64;
      w = W_hh[j * 1024 + kk] + wfb * W_lin[kk];
    }
    wv[it] = w;
    am = fmaxf(am, fabsf(w));
  }
  for (int d = 1; d < 64; d <<= 1) am = fmaxf(am, __shfl_xor(am, d));
  __shared__ float sam[4];
  if ((tid & 63) == 0) sam[tid >> 6] = am;
  __syncthreads();
  float amax = fmaxf(fmaxf(sam[0], sam[1]), fmaxf(sam[2], sam[3]));
  float sc = fmaxf(amax, 1e-30f);
  float qs = 127.0f / sc;
#pragma unroll
  for (int it = 0; it < 5; ++it) {
    int k = tid + 256 * it;
    if (k < 1088) Wq[(size_t)j * 1088 + k] = (signed char)(int)rintf(wv[it] * qs);
  }
  if (tid == 0) {
    scol[j] = sc * (1.0f / 127.0f);
    float base = b_ih[j] + b_hh[j];
    b1[j] = base + 1e-9f * wfb;      // step 1: feedback value is INIT_OUT
    b2[j] = base + b_lin[0] * wfb;   // steps >=2: folded b_lin feedback
  }
}

// ---- x -> two-channel int8, padded to 64 channels ----
__global__ void prep_x2(const float* __restrict__ x, const unsigned int* __restrict__ sxu,
                        signed char* __restrict__ xh, signed char* __restrict__ xl) {
  int idx = blockIdx.x * 256 + threadIdx.x;   // < 4194304 exactly
  int c = idx & 63;
  int bi = idx >> 6;
  float sx = fmaxf(__uint_as_float(*sxu), 1e-30f);
  float v = (c < 63) ? x[bi * 63 + c] : 0.f;
  float vn = (v / sx) * 127.0f;        // [-127, 127]
  float qh = rintf(vn);
  float ql = rintf((vn - qh) * 127.0f);
  xh[idx] = (signed char)(int)qh;
  xl[idx] = (signed char)(int)ql;
}

// ---- persistent recurrent kernel: 512 blocks (2/CU), 256 threads ----
// wave wv: weight tiles tau = 4wv+jj (jj 1..4 -> h-tiles 4wv..4wv+3;
// wave 0 also tile 0 = x). Producers for wave wv: blocks [16wv,16wv+16).
__global__ __launch_bounds__(256, 2) void lstm_rec(
    const signed char* __restrict__ Wq, const float* __restrict__ scol,
    const signed char* __restrict__ xqh, const signed char* __restrict__ xql,
    const unsigned int* __restrict__ sxu, const float* __restrict__ b1,
    const float* __restrict__ b2, const float* __restrict__ Wlin,
    signed char* __restrict__ Hhi, signed char* __restrict__ Hlo,
    float* __restrict__ outp, int* __restrict__ flags) {
  const int tid = threadIdx.x;
  const int bid = blockIdx.x;
  const int g = bid & 7;          // group: batch rows [16g,16g+16)
  const int mb = bid >> 3;        // [0,64): h-cols [16mb,16mb+16)
  const int wv = tid >> 6;
  const int ln = tid & 63;
  const int lr = ln & 15;         // MFMA fragment row/col within 16
  const int lq = ln >> 4;         // k-quarter
  const int pr = tid >> 4;        // pointwise row 0..15
  const int pc = tid & 15;        // pointwise col 0..15

  __shared__ __align__(16) float pbuf[2][4][4][16][20];  // [par][wave][gate][col][row+pad]

  // ---- B fragments (int8 weights), resident in registers: 80 VGPRs ----
  int4v bq[4][5];   // [gate][jj]; tile tau = wv*4+jj (wv>0: jj=0 loaded, unused)
#pragma unroll
  for (int q = 0; q < 4; ++q) {
    const signed char* wrow = Wq + (size_t)(q * 1024 + mb * 16 + lr) * 1088;
#pragma unroll
    for (int jj = 0; jj < 5; ++jj)
      bq[q][jj] = *reinterpret_cast<const int4v*>(wrow + (wv * 4 + jj) * 64 + lq * 16);
  }
#pragma unroll
  for (int q = 0; q < 4; ++q)
#pragma unroll
    for (int jj = 0; jj < 5; ++jj)
      asm volatile("" : "+v"(bq[q][jj]));

  // per-lane column scale (C/D col = lr)
  float scq[4];
#pragma unroll
  for (int q = 0; q < 4; ++q) scq[q] = scol[q * 1024 + mb * 16 + lr];
  const float sx = fmaxf(__uint_as_float(*sxu), 1e-30f);

  // A-frag h byte offsets (parity-independent part)
  int hoffA[4];
#pragma unroll
  for (int jj = 0; jj < 4; ++jj)
    hoffA[jj] = (g * 16 + lr) * 1024 + (wv * 4 + jj) * 64 + lq * 16;

  const int gcb = mb * 16 + pc;   // pointwise gate/h column
  float bias2[4];
#pragma unroll
  for (int q = 0; q < 4; ++q) bias2[q] = b2[q * 1024 + gcb];
  const float wl = Wlin[gcb];
  float cs = 0.f;                 // cell state (row pr), in register

  for (int t = 1; t < 512; ++t) {
    const int tm1 = t - 1;
    const int par = (t - 1) & 1;
    // --- x A-frags (wave 0 only); issued before poll, drained by poll's waits ---
    int4v axh, axl;
    if (wv == 0) {
      size_t xoff = (size_t)t * 8192 + (g * 16 + lr) * 64 + lq * 16;
      axh = *reinterpret_cast<const int4v*>(xqh + xoff);
      axl = *reinterpret_cast<const int4v*>(xql + xoff);
    }

    // --- partial wait: this wave's 16 producer blocks x 4 flags = 64, 1/lane ---
    if (t > 1) {
      const int* fp = flags + g * 256 + wv * 64 + ln;
      int guard = 0;
      for (;;) {
        int v;
        asm volatile("global_load_dword %0, %1, off sc0 sc1\n\ts_waitcnt vmcnt(0)"
                     : "=v"(v) : "v"(fp) : "memory");
        if (__all(v >= tm1)) break;
        if (++guard > (1 << 18)) break;   // hang-safety valve
      }
    }

    // --- h A-frags: two channels, direct global->register (coherence point) ---
    const signed char* Hbh = Hhi + par * 131072;
    const signed char* Hbl = Hlo + par * 131072;
    int4v ahh[4], ahl[4];
#pragma unroll
    for (int jj = 0; jj < 4; ++jj) {
      asm volatile("global_load_dwordx4 %0, %1, %2 sc0 sc1"
                   : "=v"(ahh[jj]) : "v"(hoffA[jj]), "s"(Hbh));
      asm volatile("global_load_dwordx4 %0, %1, %2 sc0 sc1"
                   : "=v"(ahl[jj]) : "v"(hoffA[jj]), "s"(Hbl));
    }
    asm volatile("s_waitcnt vmcnt(0)" ::: "memory");
    __builtin_amdgcn_sched_barrier(0);

    // --- MFMA: i32 accumulate, combine to f32 in-wave ---
    float pf[4][4];
#pragma unroll
    for (int q = 0; q < 4; ++q)
#pragma unroll
      for (int i = 0; i < 4; ++i) pf[q][i] = 0.f;
    if (wv == 0) {
#pragma unroll
      for (int q = 0; q < 4; ++q) {
        int4v xa = {0, 0, 0, 0}, xb = {0, 0, 0, 0};
        xa = MFMA_I8(axh, bq[q][0], xa);
        xb = MFMA_I8(axl, bq[q][0], xb);
#pragma unroll
        for (int i = 0; i < 4; ++i)
          pf[q][i] = sx * ((float)xa[i] * C_HI + (float)xb[i] * C_XLO);
      }
    }
#pragma unroll
    for (int q = 0; q < 4; ++q) {
      int4v hh = {0, 0, 0, 0}, hl = {0, 0, 0, 0};
#pragma unroll
      for (int jj = 0; jj < 4; ++jj) {
        hh = MFMA_I8(ahh[jj], bq[q][jj + 1], hh);
        hl = MFMA_I8(ahl[jj], bq[q][jj + 1], hl);
      }
      float4v out;
#pragma unroll
      for (int i = 0; i < 4; ++i)
        out[i] = scq[q] * (pf[q][i] + (float)hh[i] * C_HI + (float)hl[i] * C_HLO);
      *reinterpret_cast<float4v*>(&pbuf[t & 1][wv][q][lr][lq * 4]) = out;
    }
    __syncthreads();   // the ONLY barrier per step (pbuf dbuf'd by parity)

    // --- pointwise: sum 4 wave partials, gates -> c,h (1 row/thread) ---
    float ga[4];
#pragma unroll
    for (int q = 0; q < 4; ++q)
      ga[q] = pbuf[t & 1][0][q][pc][pr] + pbuf[t & 1][1][q][pc][pr] +
              pbuf[t & 1][2][q][pc][pr] + pbuf[t & 1][3][q][pc][pr];
    float lb0 = bias2[0], lb1 = bias2[1], lb2 = bias2[2], lb3 = bias2[3];
    if (t == 1) {
      lb0 = b1[gcb];
      lb1 = b1[1024 + gcb];
      lb2 = b1[2048 + gcb];
      lb3 = b1[3072 + gcb];
    }
    float iv = sigm(ga[0] + lb0), fv = sigm(ga[1] + lb1);
    float Gv = tanh_f(ga[2] + lb2), ov = sigm(ga[3] + lb3);
    cs = fv * cs + iv * Gv;
    float hv = ov * tanh_f(cs);   // |hv| < 1 strictly

    // --- quantize h to two int8 channels, publish, drain, per-wave flag ---
    float qh = rintf(hv * 127.0f);
    float ql = rintf((hv * 127.0f - qh) * 254.0f);
    int qhi = (int)qh, qlo = (int)ql;
    const int prow = g * 16 + pr;
    signed char* dh = Hhi + (t & 1) * 131072 + prow * 1024 + gcb;
    signed char* dl = Hlo + (t & 1) * 131072 + prow * 1024 + gcb;
    asm volatile("global_store_byte %0, %1, off sc0 sc1" :: "v"(dh), "v"(qhi) : "memory");
    asm volatile("global_store_byte %0, %1, off sc0 sc1" :: "v"(dl), "v"(qlo) : "memory");
    asm volatile("s_waitcnt vmcnt(0)" ::: "memory");
    if (ln == 0) {
      int* fp2 = flags + g * 256 + mb * 4 + wv;
      asm volatile("global_store_dword %0, %1, off sc0 sc1" :: "v"(fp2), "v"(t) : "memory");
    }

    // --- W_lin partial for this block's 16 cols (after flag; off-chain) ---
    float pa = hv * wl;
    pa += __shfl_xor(pa, 1);
    pa += __shfl_xor(pa, 2);
    pa += __shfl_xor(pa, 4);
    pa += __shfl_xor(pa, 8);
    if (pc == 0)
      outp[(size_t)(t * 128 + prow) * 64 + mb] = pa;
  }
}

// ---- out[t][b] = b_lin + sum_mb outp[t][b][mb]; rows t=0 -> INIT_OUT ----
__global__ void finalize(const float* __restrict__ outp, const float* __restrict__ b_lin,
                         float* __restrict__ out) {
  int tid = threadIdx.x;
  int ln = tid & 63;
  int wv = tid >> 6;
  int row = blockIdx.x * 4 + wv;   // < 65536
  float v = outp[(size_t)row * 64 + ln];
  v += __shfl_xor(v, 1);
  v += __shfl_xor(v, 2);
  v += __shfl_xor(v, 4);
  v += __shfl_xor(v, 8);
  v += __shfl_xor(v, 16);
  v += __shfl_xor(v, 32);
  if (ln == 0) out[row] = (row < 128) ? 1e-9f : (v + b_lin[0]);
}

extern "C" void kernel_launch(void* const* d_in, const int* in_sizes, int n_in,
                              void* d_out, int out_size, void* d_ws, size_t ws_size,
                              hipStream_t stream) {
  const float* x = (const float*)d_in[0];
  const float* W_ih = (const float*)d_in[1];
  const float* W_hh = (const float*)d_in[2];
  const float* b_ih = (const float*)d_in[3];
  const float* b_hh = (const float*)d_in[4];
  const float* W_lin = (const float*)d_in[5];
  const float* b_lin = (const float*)d_in[6];
  float* out = (float*)d_out;

  char* ws = (char*)d_ws;
  const size_t O_WQ   = 0;           // 4096*1088      = 4456448
  const size_t O_SCOL = 4456448;     // 16384
  const size_t O_B1   = 4472832;     // 16384
  const size_t O_B2   = 4489216;     // 16384
  const size_t O_SX   = 4505600;     // 64
  const size_t O_XH   = 4505664;     // 512*128*64     = 4194304
  const size_t O_XL   = 8699968;     // 4194304
  const size_t O_HHI  = 12894272;    // 2*128*1024     = 262144
  const size_t O_HLO  = 13156416;    // 262144
  const size_t O_FLAG = 13418560;    // 8192
  const size_t O_OUTP = 13426752;    // 512*128*64*4   = 16777216
  const size_t O_END  = 30203968;
  if (ws_size < O_END) return;       // insufficient scratch -> fail loudly

  signed char* Wq = (signed char*)(ws + O_WQ);
  float* scol = (float*)(ws + O_SCOL);
  float* b1 = (float*)(ws + O_B1);
  float* b2 = (float*)(ws + O_B2);
  unsigned int* sxu = (unsigned int*)(ws + O_SX);
  signed char* xqh = (signed char*)(ws + O_XH);
  signed char* xql = (signed char*)(ws + O_XL);
  signed char* Hhi = (signed char*)(ws + O_HHI);
  signed char* Hlo = (signed char*)(ws + O_HLO);
  int* flags = (int*)(ws + O_FLAG);
  float* outp = (float*)(ws + O_OUTP);

  initz<<<256, 256, 0, stream>>>((unsigned int*)Hhi, (unsigned int*)Hlo, flags, sxu);
  prep_ax<<<1024, 256, 0, stream>>>(x, sxu);
  prep_wq<<<4096, 256, 0, stream>>>(W_ih, W_hh, W_lin, b_ih, b_hh, b_lin, Wq, scol, b1, b2);
  prep_x2<<<16384, 256, 0, stream>>>(x, sxu, xqh, xql);
  lstm_rec<<<512, 256, 0, stream>>>(Wq, scol, xqh, xql, sxu, b1, b2, W_lin,
                                    Hhi, Hlo, outp, flags);
  finalize<<<16384, 256, 0, stream>>>(outp, b_lin, out);
}

// Round 11
// 3467.281 us; speedup vs baseline: 1.5497x; 1.5497x over previous
//
#include <hip/hip_runtime.h>
#include <stdint.h>

// NpiLstm: T=512, B=128, H=1024, IN=64 (63 x-features + 1 feedback)
// Feedback folded into recurrent weights: W_hh' = W_hh + w_fb (x) W_lin.
// R11: int8 weights LDS-RESIDENT at R5's proven geometry.
//  - R5-R8,R10: compiler NEVER keeps weights register-resident; streams
//    ~294KB(bf16)/block/step from L2 (~54B/cyc/CU => ~2.2us/step) — the
//    dominant cost. R9 proved LDS residency works but bf16 forced a bad
//    geometry. int8 (R10-proven numerics: absmax 4.88e-4) shrinks the
//    per-block weight tile to 136KB -> fits LDS at R5 geometry.
//  - 256 blocks (1/CU); 8 groups x 32 blocks; group g = batch rows
//    [16g,16g+16); block mb owns h-cols [32mb,32mb+32).
//  - waves: (kw,nw) = K-half x N-half. kw=0: x-tile + h-tiles 1..8
//    (h-cols [0,512), producers blocks 0..15); kw=1: h-tiles 9..16
//    (producers 16..31). pbuf = 2 partials only.
//  - h exchanged as two int8 channels (hi + residual) at the coherence
//    point (sc0 sc1) — proven R2/R5/R10.

typedef int int4v __attribute__((ext_vector_type(4)));
typedef float float4v __attribute__((ext_vector_type(4)));

#define C_HI  (1.0f/127.0f)
#define C_HLO (1.0f/32258.0f)   // h ~ qhi/127 + qlo/32258
#define C_XLO (1.0f/16129.0f)   // x ~ sx*(qhi/127 + qlo/16129)

__device__ __forceinline__ float sigm(float x) { return 1.0f / (1.0f + __expf(-x)); }
__device__ __forceinline__ float tanh_f(float x) {
  float ax = fabsf(x);
  float e = __expf(-2.0f * ax);
  float r = (1.0f - e) / (1.0f + e);
  return x < 0.0f ? -r : r;
}
#define MFMA_I8(A, B, C) __builtin_amdgcn_mfma_i32_16x16x64_i8((A), (B), (C), 0, 0, 0)

// ---- zero h planes + flags + sx bits (must run FIRST) ----
__global__ void initz(unsigned int* __restrict__ Hhi, unsigned int* __restrict__ Hlo,
                      int* __restrict__ flags, unsigned int* __restrict__ sxu) {
  int idx = blockIdx.x * 256 + threadIdx.x;   // 0..65535
  Hhi[idx] = 0u;                               // 2 parities x 128 x 1024 bytes
  Hlo[idx] = 0u;
  if (idx < 1024) flags[idx] = 0;
  if (idx == 0) *sxu = 0u;
}

// ---- global amax of x -> sx ----
__global__ void prep_ax(const float* __restrict__ x, unsigned int* __restrict__ sxu) {
  int tid = blockIdx.x * 256 + threadIdx.x;   // 1024 blocks
  float am = 0.f;
  for (int i = tid; i < 4128768; i += 262144) am = fmaxf(am, fabsf(x[i]));
  for (int d = 1; d < 64; d <<= 1) am = fmaxf(am, __shfl_xor(am, d));
  __shared__ float sam[4];
  if ((threadIdx.x & 63) == 0) sam[threadIdx.x >> 6] = am;
  __syncthreads();
  if (threadIdx.x == 0) {
    float m = fmaxf(fmaxf(sam[0], sam[1]), fmaxf(sam[2], sam[3]));
    atomicMax(sxu, __float_as_uint(m));   // floats >= 0: bit order = value order
  }
}

// ---- fold weights, per-column amax, quantize to int8; biases ----
// Wq row j (gate-col), k-layout: [0,64) = x-block (63 feats + 1 zero),
// [64,1088) = h-block (folded W_hh). 1088 = 17 tiles of K=64.
__global__ void prep_wq(const float* __restrict__ W_ih, const float* __restrict__ W_hh,
                        const float* __restrict__ W_lin, const float* __restrict__ b_ih,
                        const float* __restrict__ b_hh, const float* __restrict__ b_lin,
                        signed char* __restrict__ Wq, float* __restrict__ scol,
                        float* __restrict__ b1, float* __restrict__ b2) {
  int j = blockIdx.x;          // 0..4095
  int tid = threadIdx.x;
  float wfb = W_ih[j * 64 + 63];
  float wv[5];
  float am = 0.f;
#pragma unroll
  for (int it = 0; it < 5; ++it) {
    int k = tid + 256 * it;
    float w = 0.f;
    if (k < 63) w = W_ih[j * 64 + k];
    else if (k >= 64 && k < 1088) {
      int kk = k - 64;
      w = W_hh[j * 1024 + kk] + wfb * W_lin[kk];
    }
    wv[it] = w;
    am = fmaxf(am, fabsf(w));
  }
  for (int d = 1; d < 64; d <<= 1) am = fmaxf(am, __shfl_xor(am, d));
  __shared__ float sam[4];
  if ((tid & 63) == 0) sam[tid >> 6] = am;
  __syncthreads();
  float amax = fmaxf(fmaxf(sam[0], sam[1]), fmaxf(sam[2], sam[3]));
  float sc = fmaxf(amax, 1e-30f);
  float qs = 127.0f / sc;
#pragma unroll
  for (int it = 0; it < 5; ++it) {
    int k = tid + 256 * it;
    if (k < 1088) Wq[(size_t)j * 1088 + k] = (signed char)(int)rintf(wv[it] * qs);
  }
  if (tid == 0) {
    scol[j] = sc * (1.0f / 127.0f);
    float base = b_ih[j] + b_hh[j];
    b1[j] = base + 1e-9f * wfb;      // step 1: feedback value is INIT_OUT
    b2[j] = base + b_lin[0] * wfb;   // steps >=2: folded b_lin feedback
  }
}

// ---- x -> two-channel int8, padded to 64 channels ----
__global__ void prep_x2(const float* __restrict__ x, const unsigned int* __restrict__ sxu,
                        signed char* __restrict__ xh, signed char* __restrict__ xl) {
  int idx = blockIdx.x * 256 + threadIdx.x;   // < 4194304 exactly
  int c = idx & 63;
  int bi = idx >> 6;
  float sx = fmaxf(__uint_as_float(*sxu), 1e-30f);
  float v = (c < 63) ? x[bi * 63 + c] : 0.f;
  float vn = (v / sx) * 127.0f;        // [-127, 127]
  float qh = rintf(vn);
  float ql = rintf((vn - qh) * 127.0f);
  xh[idx] = (signed char)(int)qh;
  xl[idx] = (signed char)(int)ql;
}

// ---- persistent recurrent kernel: 256 blocks (1/CU), 256 threads ----
__global__ __launch_bounds__(256, 1) void lstm_rec(
    const signed char* __restrict__ Wq, const float* __restrict__ scol,
    const signed char* __restrict__ xqh, const signed char* __restrict__ xql,
    const unsigned int* __restrict__ sxu, const float* __restrict__ b1,
    const float* __restrict__ b2, const float* __restrict__ Wlin,
    signed char* __restrict__ Hhi, signed char* __restrict__ Hlo,
    float* __restrict__ outp, int* __restrict__ flags) {
  const int tid = threadIdx.x;
  const int bid = blockIdx.x;
  const int g = bid & 7;          // group: batch rows [16g,16g+16)
  const int mb = bid >> 3;        // [0,32): h-cols [32mb,32mb+32)
  const int wv = tid >> 6;
  const int ln = tid & 63;
  const int lr = ln & 15;         // MFMA fragment row/col within 16
  const int lq = ln >> 4;         // k-quarter
  const int kw = wv & 1;          // K-half
  const int nw = wv >> 1;         // N-half (ntiles nw*4 .. nw*4+4)
  const int pr = tid >> 4;        // pointwise row 0..15
  const int pc2 = tid & 15;       // pointwise col-within-half 0..15

  __shared__ __align__(16) char wlds[139264];            // [ntile 8][tau 17][1024B]
  __shared__ __align__(16) float pbuf[2][8][16][20];     // [kw][ntile][col][row+pad]

  // ---- stage int8 weight fragments to LDS, ONCE (B-frag layout) ----
  for (int s = tid; s < 8704; s += 256) {    // 8*17*64 slots
    int nt = s / 1088;                        // ntile = gate*2 + colhalf
    int rem = s - nt * 1088;
    int tau = rem >> 6;                       // K-tile 0..16
    int l = rem & 63;                         // fragment lane slot
    int row = (nt >> 1) * 1024 + mb * 32 + (nt & 1) * 16 + (l & 15);
    int4v v = *reinterpret_cast<const int4v*>(
        Wq + (size_t)row * 1088 + tau * 64 + (l >> 4) * 16);
    *reinterpret_cast<int4v*>(wlds + (nt * 17 + tau) * 1024 + l * 16) = v;
  }
  __syncthreads();

  // per-lane column scales for this wave's 4 ntiles (C/D col = lr)
  float scq[4];
#pragma unroll
  for (int j = 0; j < 4; ++j) {
    int nt = nw * 4 + j;
    scq[j] = scol[(nt >> 1) * 1024 + mb * 32 + (nt & 1) * 16 + lr];
  }
  const float sx = fmaxf(__uint_as_float(*sxu), 1e-30f);

  // A h-frag byte offsets within a parity plane; tau0 = first h-tile
  const int tau0 = kw ? 9 : 1;
  int hoff[8];
#pragma unroll
  for (int j = 0; j < 8; ++j)
    hoff[j] = (g * 16 + lr) * 1024 + (tau0 + j - 1) * 64 + lq * 16;

  // pointwise per-thread constants (cols c0 = mb*32+pc2, c1 = c0+16)
  const int c0 = mb * 32 + pc2;
  const int c1 = c0 + 16;
  float bias2[4][2];
#pragma unroll
  for (int q = 0; q < 4; ++q) {
    bias2[q][0] = b2[q * 1024 + c0];
    bias2[q][1] = b2[q * 1024 + c1];
  }
  const float wl0 = Wlin[c0], wl1 = Wlin[c1];
  float cs0 = 0.f, cs1 = 0.f;     // cell states (row pr, cols c0/c1)

  for (int t = 1; t < 512; ++t) {
    const int tm1 = t - 1;
    const int par = (t - 1) & 1;
    // --- x A-frags (kw==0 waves only; plain cached loads) ---
    int4v axh, axl;
    if (kw == 0) {
      size_t xoff = (size_t)t * 8192 + (g * 16 + lr) * 64 + lq * 16;
      axh = *reinterpret_cast<const int4v*>(xqh + xoff);
      axl = *reinterpret_cast<const int4v*>(xql + xoff);
    }

    // --- partial wait: this K-half's 16 producer blocks x 4 flags = 64 ---
    if (t > 1) {
      const int* fp = flags + g * 128 + kw * 64 + ln;
      int guard = 0;
      for (;;) {
        int v;
        asm volatile("global_load_dword %0, %1, off sc0 sc1\n\ts_waitcnt vmcnt(0)"
                     : "=v"(v) : "v"(fp) : "memory");
        if (__all(v >= tm1)) break;
        if (++guard > (1 << 18)) break;   // hang-safety valve
      }
    }

    // --- h A-frags: two channels, direct global->register (coherence pt) ---
    const signed char* Hbh = Hhi + par * 131072;
    const signed char* Hbl = Hlo + par * 131072;
    int4v ahh[8], ahl[8];
#pragma unroll
    for (int j = 0; j < 8; ++j) {
      asm volatile("global_load_dwordx4 %0, %1, %2 sc0 sc1"
                   : "=v"(ahh[j]) : "v"(hoff[j]), "s"(Hbh));
      asm volatile("global_load_dwordx4 %0, %1, %2 sc0 sc1"
                   : "=v"(ahl[j]) : "v"(hoff[j]), "s"(Hbl));
    }
    asm volatile("s_waitcnt vmcnt(0)" ::: "memory");
    __builtin_amdgcn_sched_barrier(0);

    // --- MFMA: weights from LDS (resident), i32 acc, combine to f32 ---
    float pf[4][4];
#pragma unroll
    for (int j = 0; j < 4; ++j)
#pragma unroll
      for (int i = 0; i < 4; ++i) pf[j][i] = 0.f;
    if (kw == 0) {
#pragma unroll
      for (int j = 0; j < 4; ++j) {
        int nt = nw * 4 + j;
        const int4v bx = *reinterpret_cast<const int4v*>(
            wlds + (nt * 17 + 0) * 1024 + ln * 16);
        int4v xa = {0, 0, 0, 0}, xb = {0, 0, 0, 0};
        xa = MFMA_I8(axh, bx, xa);
        xb = MFMA_I8(axl, bx, xb);
#pragma unroll
        for (int i = 0; i < 4; ++i)
          pf[j][i] = sx * ((float)xa[i] * C_HI + (float)xb[i] * C_XLO);
      }
    }
    int4v hh[4], hl[4];
#pragma unroll
    for (int j = 0; j < 4; ++j) {
      hh[j] = (int4v){0, 0, 0, 0};
      hl[j] = (int4v){0, 0, 0, 0};
    }
#pragma unroll
    for (int tj = 0; tj < 8; ++tj) {
#pragma unroll
      for (int j = 0; j < 4; ++j) {
        int nt = nw * 4 + j;
        const int4v bf = *reinterpret_cast<const int4v*>(
            wlds + (nt * 17 + tau0 + tj) * 1024 + ln * 16);
        hh[j] = MFMA_I8(ahh[tj], bf, hh[j]);
        hl[j] = MFMA_I8(ahl[tj], bf, hl[j]);
      }
    }
#pragma unroll
    for (int j = 0; j < 4; ++j) {
      float4v o;
#pragma unroll
      for (int i = 0; i < 4; ++i)
        o[i] = scq[j] * (pf[j][i] + (float)hh[j][i] * C_HI + (float)hl[j][i] * C_HLO);
      *reinterpret_cast<float4v*>(&pbuf[kw][nw * 4 + j][lr][lq * 4]) = o;
    }
    __syncthreads();   // bar1: partials visible

    // --- pointwise: sum 2 K-half partials, gates -> c,h (2 cols/thread) ---
    float ga0[4], ga1[4];
#pragma unroll
    for (int q = 0; q < 4; ++q) {
      ga0[q] = pbuf[0][q * 2][pc2][pr] + pbuf[1][q * 2][pc2][pr];
      ga1[q] = pbuf[0][q * 2 + 1][pc2][pr] + pbuf[1][q * 2 + 1][pc2][pr];
    }
    __syncthreads();   // bar2: pbuf reads done before next step's writes

    float lb[4][2];
    if (t == 1) {
#pragma unroll
      for (int q = 0; q < 4; ++q) {
        lb[q][0] = b1[q * 1024 + c0];
        lb[q][1] = b1[q * 1024 + c1];
      }
    } else {
#pragma unroll
      for (int q = 0; q < 4; ++q) { lb[q][0] = bias2[q][0]; lb[q][1] = bias2[q][1]; }
    }
    float i0 = sigm(ga0[0] + lb[0][0]), f0 = sigm(ga0[1] + lb[1][0]);
    float G0 = tanh_f(ga0[2] + lb[2][0]), o0 = sigm(ga0[3] + lb[3][0]);
    float i1 = sigm(ga1[0] + lb[0][1]), f1 = sigm(ga1[1] + lb[1][1]);
    float G1 = tanh_f(ga1[2] + lb[2][1]), o1 = sigm(ga1[3] + lb[3][1]);
    cs0 = f0 * cs0 + i0 * G0;
    cs1 = f1 * cs1 + i1 * G1;
    float hv0 = o0 * tanh_f(cs0);
    float hv1 = o1 * tanh_f(cs1);

    // --- quantize h to two int8 channels, publish, drain, per-wave flag ---
    float qh0 = rintf(hv0 * 127.0f), ql0 = rintf((hv0 * 127.0f - qh0) * 254.0f);
    float qh1 = rintf(hv1 * 127.0f), ql1 = rintf((hv1 * 127.0f - qh1) * 254.0f);
    int ih0 = (int)qh0, il0 = (int)ql0, ih1 = (int)qh1, il1 = (int)ql1;
    const int prow = g * 16 + pr;
    signed char* dh = Hhi + (t & 1) * 131072 + prow * 1024;
    signed char* dl = Hlo + (t & 1) * 131072 + prow * 1024;
    asm volatile("global_store_byte %0, %1, off sc0 sc1" :: "v"(dh + c0), "v"(ih0) : "memory");
    asm volatile("global_store_byte %0, %1, off sc0 sc1" :: "v"(dl + c0), "v"(il0) : "memory");
    asm volatile("global_store_byte %0, %1, off sc0 sc1" :: "v"(dh + c1), "v"(ih1) : "memory");
    asm volatile("global_store_byte %0, %1, off sc0 sc1" :: "v"(dl + c1), "v"(il1) : "memory");
    asm volatile("s_waitcnt vmcnt(0)" ::: "memory");
    if (ln == 0) {
      int* fp2 = flags + g * 128 + mb * 4 + wv;
      asm volatile("global_store_dword %0, %1, off sc0 sc1" :: "v"(fp2), "v"(t) : "memory");
    }

    // --- W_lin partial for this block's 32 cols (after flag; off-chain) ---
    float pa = hv0 * wl0 + hv1 * wl1;
    pa += __shfl_xor(pa, 1);
    pa += __shfl_xor(pa, 2);
    pa += __shfl_xor(pa, 4);
    pa += __shfl_xor(pa, 8);
    if (pc2 == 0)
      outp[(size_t)(t * 128 + prow) * 32 + mb] = pa;
  }
}

// ---- out[t][b] = b_lin + sum_mb outp[t][b][mb]; rows t=0 -> INIT_OUT ----
__global__ void finalize(const float* __restrict__ outp, const float* __restrict__ b_lin,
                         float* __restrict__ out) {
  int tid = threadIdx.x;
  int ln = tid & 63;
  int wv = tid >> 6;
  int half = ln >> 5;
  int lane = ln & 31;
  int row = blockIdx.x * 8 + wv * 2 + half;   // < 65536
  float v = outp[(size_t)row * 32 + lane];
  v += __shfl_xor(v, 1);
  v += __shfl_xor(v, 2);
  v += __shfl_xor(v, 4);
  v += __shfl_xor(v, 8);
  v += __shfl_xor(v, 16);
  if (lane == 0) out[row] = (row < 128) ? 1e-9f : (v + b_lin[0]);
}

extern "C" void kernel_launch(void* const* d_in, const int* in_sizes, int n_in,
                              void* d_out, int out_size, void* d_ws, size_t ws_size,
                              hipStream_t stream) {
  const float* x = (const float*)d_in[0];
  const float* W_ih = (const float*)d_in[1];
  const float* W_hh = (const float*)d_in[2];
  const float* b_ih = (const float*)d_in[3];
  const float* b_hh = (const float*)d_in[4];
  const float* W_lin = (const float*)d_in[5];
  const float* b_lin = (const float*)d_in[6];
  float* out = (float*)d_out;

  char* ws = (char*)d_ws;
  const size_t O_WQ   = 0;           // 4096*1088      = 4456448
  const size_t O_SCOL = 4456448;     // 16384
  const size_t O_B1   = 4472832;     // 16384
  const size_t O_B2   = 4489216;     // 16384
  const size_t O_SX   = 4505600;     // 64
  const size_t O_XH   = 4505664;     // 512*128*64     = 4194304
  const size_t O_XL   = 8699968;     // 4194304
  const size_t O_HHI  = 12894272;    // 2*128*1024     = 262144
  const size_t O_HLO  = 13156416;    // 262144
  const size_t O_FLAG = 13418560;    // 8192
  const size_t O_OUTP = 13426752;    // 512*128*32*4   = 8388608
  const size_t O_END  = 21815360;
  if (ws_size < O_END) return;       // insufficient scratch -> fail loudly

  signed char* Wq = (signed char*)(ws + O_WQ);
  float* scol = (float*)(ws + O_SCOL);
  float* b1 = (float*)(ws + O_B1);
  float* b2 = (float*)(ws + O_B2);
  unsigned int* sxu = (unsigned int*)(ws + O_SX);
  signed char* xqh = (signed char*)(ws + O_XH);
  signed char* xql = (signed char*)(ws + O_XL);
  signed char* Hhi = (signed char*)(ws + O_HHI);
  signed char* Hlo = (signed char*)(ws + O_HLO);
  int* flags = (int*)(ws + O_FLAG);
  float* outp = (float*)(ws + O_OUTP);

  initz<<<256, 256, 0, stream>>>((unsigned int*)Hhi, (unsigned int*)Hlo, flags, sxu);
  prep_ax<<<1024, 256, 0, stream>>>(x, sxu);
  prep_wq<<<4096, 256, 0, stream>>>(W_ih, W_hh, W_lin, b_ih, b_hh, b_lin, Wq, scol, b1, b2);
  prep_x2<<<16384, 256, 0, stream>>>(x, sxu, xqh, xql);
  lstm_rec<<<256, 256, 0, stream>>>(Wq, scol, xqh, xql, sxu, b1, b2, W_lin,
                                    Hhi, Hlo, outp, flags);
  finalize<<<8192, 256, 0, stream>>>(outp, b_lin, out);
}